// Round 1
// baseline (254.371 us; speedup 1.0000x reference)
//
#include <hip/hip_runtime.h>
#include <stdint.h>

#define TOK 8192
#define EDIM 1024
#define NH 16
#define HD 64
#define SEQ 1024
#define BATCH 8

typedef short bf16x8 __attribute__((ext_vector_type(8)));
typedef short bf16x4 __attribute__((ext_vector_type(4)));
typedef float f32x4 __attribute__((ext_vector_type(4)));

__device__ __forceinline__ short f2bf(float f) {
  union { float f; uint32_t u; } c; c.f = f;
  uint32_t u = c.u;
  u += 0x7FFFu + ((u >> 16) & 1u);   // RNE
  return (short)(u >> 16);
}
__device__ __forceinline__ float bf2f(short h) {
  union { uint32_t u; float f; } c; c.u = ((uint32_t)(uint16_t)h) << 16;
  return c.f;
}

#define GLDS16(ldsp, gp) __builtin_amdgcn_global_load_lds( \
    (__attribute__((address_space(1))) void*)(gp),          \
    (__attribute__((address_space(3))) void*)(ldsp), 16, 0, 0)

// ---------------------------------------------------------------- cast
__global__ void cast_f32_bf16(const float* __restrict__ src, short* __restrict__ dst, int n) {
  int i = (blockIdx.x * 256 + threadIdx.x) * 4;
  if (i >= n) return;
  float4 f = *(const float4*)(src + i);
  bf16x4 o;
  o[0] = f2bf(f.x); o[1] = f2bf(f.y); o[2] = f2bf(f.z); o[3] = f2bf(f.w);
  *(bf16x4*)(dst + i) = o;
}

// ---------------------------------------------------------------- GEMM (m97 structure)
// A [M,K] row-major bf16, Bw [N,K] row-major bf16 (i.e. B^T input), K=N=1024, M=8192.
// MODE 0: qkv projection, z in {0,1,2}; out = bf16 [B,H,S,D]. MODE 1: out proj, fp32 [B,S,E].
template<int MODE>
__global__ __launch_bounds__(256)
void gemm_bt(const short* __restrict__ Abase, const short* __restrict__ Wbase,
             const float* __restrict__ biasBase, void* __restrict__ outv) {
  int z = (MODE == 0) ? blockIdx.z : 0;
  const size_t NTOK = (size_t)TOK * EDIM;
  const short* A  = Abase + (size_t)z * NTOK;
  const short* Bw = Wbase + (size_t)z * EDIM * EDIM;
  const float* bias = biasBase + z * EDIM;

  __shared__ short As[128 * 32];
  __shared__ short Bs[128 * 32];

  int t = threadIdx.x;
  int l = t & 63, w = t >> 6;
  int wr = w >> 1, wc = w & 1;
  int fr = l & 15, fg = l >> 4;
  int rowBase = blockIdx.x * 128;
  int colBase = blockIdx.y * 128;

  f32x4 acc[4][4];
  for (int i = 0; i < 4; i++)
    for (int j = 0; j < 4; j++) acc[i][j] = (f32x4){0.f, 0.f, 0.f, 0.f};

  int sRow = t >> 2;
  int sCol = (t & 3) * 8;
  const short* aSrc = A  + (size_t)(rowBase + sRow) * EDIM + sCol;
  const short* bSrc = Bw + (size_t)(colBase + sRow) * EDIM + sCol;
  short* aDst = &As[t * 8];
  short* bDst = &Bs[t * 8];

  for (int k0 = 0; k0 < EDIM; k0 += 32) {
    GLDS16(aDst,        aSrc + k0);
    GLDS16(aDst + 2048, aSrc + (size_t)64 * EDIM + k0);
    GLDS16(bDst,        bSrc + k0);
    GLDS16(bDst + 2048, bSrc + (size_t)64 * EDIM + k0);
    __syncthreads();

    bf16x8 af[4], bf_[4];
    for (int mi = 0; mi < 4; mi++)
      af[mi] = *(const bf16x8*)&As[(wr * 64 + mi * 16 + fr) * 32 + fg * 8];
    for (int ni = 0; ni < 4; ni++)
      bf_[ni] = *(const bf16x8*)&Bs[(wc * 64 + ni * 16 + fr) * 32 + fg * 8];
    for (int mi = 0; mi < 4; mi++)
      for (int ni = 0; ni < 4; ni++)
        acc[mi][ni] = __builtin_amdgcn_mfma_f32_16x16x32_bf16(af[mi], bf_[ni], acc[mi][ni], 0, 0, 0);
    __syncthreads();
  }

  for (int mi = 0; mi < 4; mi++)
    for (int ni = 0; ni < 4; ni++)
      for (int r = 0; r < 4; r++) {
        int grow = rowBase + wr * 64 + mi * 16 + fg * 4 + r;   // token
        int gcol = colBase + wc * 64 + ni * 16 + fr;           // output feature
        float v = acc[mi][ni][r] + bias[gcol];
        if (MODE == 0) {
          int b_ = grow >> 10, s_ = grow & 1023;
          int h_ = gcol >> 6,  d_ = gcol & 63;
          short* outp = (short*)outv + (size_t)z * NTOK;
          outp[((size_t)((b_ * NH + h_) * SEQ + s_) << 6) | d_] = f2bf(v);
        } else {
          ((float*)outv)[(size_t)grow * EDIM + gcol] = v;
        }
      }
}

// ---------------------------------------------------------------- flash attention
// proj: qp|kp|vp each [B,H,S,D] bf16. ctx out: [B,S,E] bf16.
__global__ __launch_bounds__(256)
void attn_fwd(const short* __restrict__ proj, short* __restrict__ ctx) {
  __shared__ short Ks[64 * 64];   // [kv][d], rows XOR-swizzled in 16B chunks
  __shared__ short Vt[64 * 64];   // [d][kv], swizzled
  __shared__ short Ps[128 * 64];  // [q][kv], swizzled, per-wave 32-row slices

  int t = threadIdx.x;
  int l = t & 63, w = t >> 6;
  int fr = l & 15, fg = l >> 4;
  int qt = blockIdx.x, h = blockIdx.y, b = blockIdx.z;

  size_t headOff = (size_t)(b * NH + h) * SEQ * HD;
  const size_t NTOK = (size_t)TOK * EDIM;
  const short* Qp = proj + headOff;
  const short* Kp = proj + NTOK + headOff;
  const short* Vp = proj + 2 * NTOK + headOff;

  int q0 = qt * 128;

  // Q fragments, pre-scaled by 1/sqrt(D)=0.125 (exact in bf16)
  bf16x8 aQ[2][2];
  for (int mi = 0; mi < 2; mi++)
    for (int kk = 0; kk < 2; kk++) {
      bf16x8 v = *(const bf16x8*)(Qp + (size_t)(q0 + w * 32 + mi * 16 + fr) * HD + kk * 32 + fg * 8);
      for (int j = 0; j < 8; j++) v[j] = f2bf(bf2f(v[j]) * 0.125f);
      aQ[mi][kk] = v;
    }

  float m_run[2][4], l_run[2][4];
  f32x4 o[2][4];
  for (int mi = 0; mi < 2; mi++)
    for (int r = 0; r < 4; r++) { m_run[mi][r] = -3.0e38f; l_run[mi][r] = 0.f; }
  for (int mi = 0; mi < 2; mi++)
    for (int nd = 0; nd < 4; nd++) o[mi][nd] = (f32x4){0.f, 0.f, 0.f, 0.f};

  for (int j = 0; j < SEQ / 64; j++) {
    int kv0 = j * 64;
    // stage K: pre-swizzled global source -> linear LDS dest (global_load_lds)
    {
      int r1 = t >> 3, c = t & 7;
      GLDS16(&Ks[t * 8],        Kp + (size_t)(kv0 + r1) * HD + ((c ^ (r1 & 7)) * 8));
      int r2 = r1 + 32;
      GLDS16(&Ks[t * 8 + 2048], Kp + (size_t)(kv0 + r2) * HD + ((c ^ (r2 & 7)) * 8));
    }
    // stage V transposed (reg path, swizzled scatter writes)
    {
      int kv = l;
      for (int i = 0; i < 2; i++) {
        int dbase = w * 8 + i * 32;
        bf16x8 vv = *(const bf16x8*)(Vp + (size_t)(kv0 + kv) * HD + dbase);
        for (int jj = 0; jj < 8; jj++) {
          int d = dbase + jj;
          int byteoff = d * 128 + (((kv >> 3) ^ (d & 7)) << 4) + (kv & 7) * 2;
          *(short*)((char*)Vt + byteoff) = vv[jj];
        }
      }
    }
    __syncthreads();

    // QK^T: S[32q x 64kv] per wave
    f32x4 sacc[2][4];
    for (int mi = 0; mi < 2; mi++)
      for (int ni = 0; ni < 4; ni++) sacc[mi][ni] = (f32x4){0.f, 0.f, 0.f, 0.f};
    for (int kk = 0; kk < 2; kk++) {
      bf16x8 bK[4];
      int cb = kk * 4 + fg;
      for (int ni = 0; ni < 4; ni++) {
        int n = ni * 16 + fr;
        bK[ni] = *(const bf16x8*)((const char*)Ks + n * 128 + ((cb ^ (n & 7)) << 4));
      }
      for (int mi = 0; mi < 2; mi++)
        for (int ni = 0; ni < 4; ni++)
          sacc[mi][ni] = __builtin_amdgcn_mfma_f32_16x16x32_bf16(aQ[mi][kk], bK[ni], sacc[mi][ni], 0, 0, 0);
    }

    // online softmax (rows spread over 16 lanes: fr varies; reduce via shfl_xor 1,2,4,8)
    float alpha[2][4];
    for (int mi = 0; mi < 2; mi++)
      for (int r = 0; r < 4; r++) {
        float vmax = fmaxf(fmaxf(sacc[mi][0][r], sacc[mi][1][r]),
                           fmaxf(sacc[mi][2][r], sacc[mi][3][r]));
        vmax = fmaxf(vmax, __shfl_xor(vmax, 1));
        vmax = fmaxf(vmax, __shfl_xor(vmax, 2));
        vmax = fmaxf(vmax, __shfl_xor(vmax, 4));
        vmax = fmaxf(vmax, __shfl_xor(vmax, 8));
        float m_new = fmaxf(m_run[mi][r], vmax);
        alpha[mi][r] = __expf(m_run[mi][r] - m_new);
        m_run[mi][r] = m_new;
        float s0 = 0.f;
        for (int ni = 0; ni < 4; ni++) {
          float p = __expf(sacc[mi][ni][r] - m_new);
          sacc[mi][ni][r] = p;
          s0 += p;
        }
        s0 += __shfl_xor(s0, 1);
        s0 += __shfl_xor(s0, 2);
        s0 += __shfl_xor(s0, 4);
        s0 += __shfl_xor(s0, 8);
        l_run[mi][r] = l_run[mi][r] * alpha[mi][r] + s0;
      }

    // P -> bf16 -> LDS (own wave's 32-row slice; swizzled)
    for (int mi = 0; mi < 2; mi++)
      for (int ni = 0; ni < 4; ni++)
        for (int r = 0; r < 4; r++) {
          int q = w * 32 + mi * 16 + fg * 4 + r;
          int kv = ni * 16 + fr;
          int byteoff = q * 128 + (((kv >> 3) ^ (q & 7)) << 4) + (kv & 7) * 2;
          *(short*)((char*)Ps + byteoff) = f2bf(sacc[mi][ni][r]);
        }
    // rescale O
    for (int mi = 0; mi < 2; mi++)
      for (int nd = 0; nd < 4; nd++)
        for (int r = 0; r < 4; r++) o[mi][nd][r] *= alpha[mi][r];

    // PV: O[32q x 64d] += P[32q x 64kv] @ V[64kv x 64d]
    for (int kk = 0; kk < 2; kk++) {
      bf16x8 aP[2], bV[4];
      int cb = kk * 4 + fg;
      for (int mi = 0; mi < 2; mi++) {
        int q = w * 32 + mi * 16 + fr;
        aP[mi] = *(const bf16x8*)((const char*)Ps + q * 128 + ((cb ^ (q & 7)) << 4));
      }
      for (int nd = 0; nd < 4; nd++) {
        int d = nd * 16 + fr;
        bV[nd] = *(const bf16x8*)((const char*)Vt + d * 128 + ((cb ^ (d & 7)) << 4));
      }
      for (int mi = 0; mi < 2; mi++)
        for (int nd = 0; nd < 4; nd++)
          o[mi][nd] = __builtin_amdgcn_mfma_f32_16x16x32_bf16(aP[mi], bV[nd], o[mi][nd], 0, 0, 0);
    }
    __syncthreads();
  }

  // epilogue: O / l, write ctx [B,S,E] bf16
  for (int mi = 0; mi < 2; mi++)
    for (int nd = 0; nd < 4; nd++)
      for (int r = 0; r < 4; r++) {
        int q = q0 + w * 32 + mi * 16 + fg * 4 + r;
        int d = nd * 16 + fr;
        float v = o[mi][nd][r] / l_run[mi][r];
        ctx[(size_t)(b * SEQ + q) * EDIM + h * HD + d] = f2bf(v);
      }
}

// ---------------------------------------------------------------- launch
extern "C" void kernel_launch(void* const* d_in, const int* in_sizes, int n_in,
                              void* d_out, int out_size, void* d_ws, size_t ws_size,
                              hipStream_t stream) {
  const float* q  = (const float*)d_in[0];
  const float* k  = (const float*)d_in[1];
  const float* v  = (const float*)d_in[2];
  const float* wi = (const float*)d_in[3];
  const float* bi = (const float*)d_in[4];
  const float* wo = (const float*)d_in[5];
  const float* bo = (const float*)d_in[6];
  float* out = (float*)d_out;

  short* ws = (short*)d_ws;
  const size_t NTOK = (size_t)TOK * EDIM;               // 8388608
  short* qkv_bf   = ws;                                 // 3*NTOK shorts
  short* w_in_bf  = qkv_bf + 3 * NTOK;                  // 3*E*E
  short* w_out_bf = w_in_bf + 3 * (size_t)EDIM * EDIM;  // E*E
  short* proj_bf  = w_out_bf + (size_t)EDIM * EDIM;     // 3*NTOK
  short* ctx_bf   = qkv_bf;                             // reuse q region (done being read)

  cast_f32_bf16<<<dim3((unsigned)(NTOK / 4 / 256)), 256, 0, stream>>>(q, qkv_bf, (int)NTOK);
  cast_f32_bf16<<<dim3((unsigned)(NTOK / 4 / 256)), 256, 0, stream>>>(k, qkv_bf + NTOK, (int)NTOK);
  cast_f32_bf16<<<dim3((unsigned)(NTOK / 4 / 256)), 256, 0, stream>>>(v, qkv_bf + 2 * NTOK, (int)NTOK);
  cast_f32_bf16<<<dim3(3 * EDIM * EDIM / 4 / 256), 256, 0, stream>>>(wi, w_in_bf, 3 * EDIM * EDIM);
  cast_f32_bf16<<<dim3(EDIM * EDIM / 4 / 256), 256, 0, stream>>>(wo, w_out_bf, EDIM * EDIM);

  gemm_bt<0><<<dim3(TOK / 128, EDIM / 128, 3), 256, 0, stream>>>(qkv_bf, w_in_bf, bi, proj_bf);
  attn_fwd<<<dim3(SEQ / 128, NH, BATCH), 256, 0, stream>>>(proj_bf, ctx_bf);
  gemm_bt<1><<<dim3(TOK / 128, EDIM / 128, 1), 256, 0, stream>>>(ctx_bf, w_out_bf, bo, out);
}

// Round 4
// 227.174 us; speedup vs baseline: 1.1197x; 1.1197x over previous
//
#include <hip/hip_runtime.h>
#include <stdint.h>

#define TOK 8192
#define EDIM 1024
#define NH 16
#define HD 64
#define SEQ 1024
#define BATCH 8

typedef short bf16x8 __attribute__((ext_vector_type(8)));
typedef short bf16x4 __attribute__((ext_vector_type(4)));
typedef float f32x4 __attribute__((ext_vector_type(4)));
typedef float f32x16 __attribute__((ext_vector_type(16)));
typedef unsigned int u32x4 __attribute__((ext_vector_type(4)));

__device__ __forceinline__ short f2bf(float f) {
  union { float f; uint32_t u; } c; c.f = f;
  uint32_t u = c.u;
  u += 0x7FFFu + ((u >> 16) & 1u);   // RNE
  return (short)(u >> 16);
}
__device__ __forceinline__ float bf2f(short h) {
  union { uint32_t u; float f; } c; c.u = ((uint32_t)(uint16_t)h) << 16;
  return c.f;
}
__device__ __forceinline__ uint32_t bfr(float f) {  // cheap round-half-up
  union { float f; uint32_t u; } c; c.f = f;
  return (c.u + 0x8000u) >> 16;
}
__device__ __forceinline__ uint32_t pk2(float lo, float hi_) {
  return (bfr(hi_) << 16) | (bfr(lo) & 0xffffu);
}

#define GLDS16(ldsp, gp) __builtin_amdgcn_global_load_lds( \
    (__attribute__((address_space(1))) void*)(gp),          \
    (__attribute__((address_space(3))) void*)(ldsp), 16, 0, 0)

// ---------------------------------------------------------------- cast
__global__ void cast_f32_bf16(const float* __restrict__ src, short* __restrict__ dst, int n) {
  int i = (blockIdx.x * 256 + threadIdx.x) * 4;
  if (i >= n) return;
  float4 f = *(const float4*)(src + i);
  bf16x4 o;
  o[0] = f2bf(f.x); o[1] = f2bf(f.y); o[2] = f2bf(f.z); o[3] = f2bf(f.w);
  *(bf16x4*)(dst + i) = o;
}

// ---------------------------------------------------------------- GEMM (m97 structure)
template<int MODE>
__global__ __launch_bounds__(256)
void gemm_bt(const short* __restrict__ Abase, const short* __restrict__ Wbase,
             const float* __restrict__ biasBase, void* __restrict__ outv) {
  int z = (MODE == 0) ? blockIdx.z : 0;
  const size_t NTOK = (size_t)TOK * EDIM;
  const short* A  = Abase + (size_t)z * NTOK;
  const short* Bw = Wbase + (size_t)z * EDIM * EDIM;
  const float* bias = biasBase + z * EDIM;

  __shared__ short As[128 * 32];
  __shared__ short Bs[128 * 32];

  int t = threadIdx.x;
  int l = t & 63, w = t >> 6;
  int wr = w >> 1, wc = w & 1;
  int fr = l & 15, fg = l >> 4;
  int rowBase = blockIdx.x * 128;
  int colBase = blockIdx.y * 128;

  f32x4 acc[4][4];
  for (int i = 0; i < 4; i++)
    for (int j = 0; j < 4; j++) acc[i][j] = (f32x4){0.f, 0.f, 0.f, 0.f};

  int sRow = t >> 2;
  int sCol = (t & 3) * 8;
  const short* aSrc = A  + (size_t)(rowBase + sRow) * EDIM + sCol;
  const short* bSrc = Bw + (size_t)(colBase + sRow) * EDIM + sCol;
  short* aDst = &As[t * 8];
  short* bDst = &Bs[t * 8];

  for (int k0 = 0; k0 < EDIM; k0 += 32) {
    GLDS16(aDst,        aSrc + k0);
    GLDS16(aDst + 2048, aSrc + (size_t)64 * EDIM + k0);
    GLDS16(bDst,        bSrc + k0);
    GLDS16(bDst + 2048, bSrc + (size_t)64 * EDIM + k0);
    __syncthreads();

    bf16x8 af[4], bf_[4];
    for (int mi = 0; mi < 4; mi++)
      af[mi] = *(const bf16x8*)&As[(wr * 64 + mi * 16 + fr) * 32 + fg * 8];
    for (int ni = 0; ni < 4; ni++)
      bf_[ni] = *(const bf16x8*)&Bs[(wc * 64 + ni * 16 + fr) * 32 + fg * 8];
    for (int mi = 0; mi < 4; mi++)
      for (int ni = 0; ni < 4; ni++)
        acc[mi][ni] = __builtin_amdgcn_mfma_f32_16x16x32_bf16(af[mi], bf_[ni], acc[mi][ni], 0, 0, 0);
    __syncthreads();
  }

  for (int mi = 0; mi < 4; mi++)
    for (int ni = 0; ni < 4; ni++)
      for (int r = 0; r < 4; r++) {
        int grow = rowBase + wr * 64 + mi * 16 + fg * 4 + r;
        int gcol = colBase + wc * 64 + ni * 16 + fr;
        float v = acc[mi][ni][r] + bias[gcol];
        if (MODE == 0) {
          int b_ = grow >> 10, s_ = grow & 1023;
          int h_ = gcol >> 6,  d_ = gcol & 63;
          short* outp = (short*)outv + (size_t)z * NTOK;
          outp[((size_t)((b_ * NH + h_) * SEQ + s_) << 6) | d_] = f2bf(v);
        } else {
          ((float*)outv)[(size_t)grow * EDIM + gcol] = v;
        }
      }
}

// ---------------------------------------------------------------- flash attention v2
// Swapped-operand structure: S^T = K·Q^T (lane owns q = lane&31 column),
// in-register softmax, P repacked to bf16 PV fragments via one shfl_xor(32)
// exchange per packed word pair, O^T = V^T·P^T (in-lane rescale/divide).
// Epilogue transposes via LDS once per block.
__global__ __launch_bounds__(256)
void attn_fwd2(const short* __restrict__ proj, short* __restrict__ ctx) {
  __shared__ short lds[128 * 64];          // 16 KiB: Ks[64][64] | Vt[64][64]; reused by epilogue
  short* Ks = lds;
  short* Vt = lds + 64 * 64;

  const int t = threadIdx.x;
  const int l = t & 63, w = t >> 6;
  const int ln = l & 31, hi = l >> 5;
  const int qt = blockIdx.x, h = blockIdx.y, b = blockIdx.z;

  const size_t NTOK = (size_t)TOK * EDIM;
  const size_t headOff = (size_t)(b * NH + h) * SEQ * HD;
  const short* Qp = proj + headOff;
  const short* Kp = proj + NTOK + headOff;
  const short* Vp = proj + 2 * NTOK + headOff;

  const int q0 = qt * 128;
  const int qrow = q0 + w * 32 + ln;      // lane & lane^32 share this q row

  // Q^T B-fragments: lane holds Q[qrow][ds*16 + hi*8 + j], scaled by 0.125*log2(e)
  const float qscale = 0.18033688011112042f;
  bf16x8 bQ[4];
#pragma unroll
  for (int ds = 0; ds < 4; ds++) {
    bf16x8 v = *(const bf16x8*)(Qp + (size_t)qrow * HD + ds * 16 + hi * 8);
#pragma unroll
    for (int j = 0; j < 8; j++) v[j] = (short)bfr(bf2f(v[j]) * qscale);
    bQ[ds] = v;
  }

  float m_run = -3.0e38f, l_run = 0.f;
  f32x16 ot[2];
#pragma unroll
  for (int i = 0; i < 16; i++) { ot[0][i] = 0.f; ot[1][i] = 0.f; }

  for (int jt = 0; jt < SEQ / 64; jt++) {
    const int kv0 = jt * 64;
    // ---- stage K via global_load_lds (pre-swizzled source, linear dest)
    {
      int r1 = t >> 3, c = t & 7;
      GLDS16(&Ks[t * 8],        Kp + (size_t)(kv0 + r1) * HD + ((c ^ (r1 & 7)) * 8));
      int r2 = r1 + 32;
      GLDS16(&Ks[t * 8 + 2048], Kp + (size_t)(kv0 + r2) * HD + ((c ^ (r2 & 7)) * 8));
    }
    // ---- stage V transposed (register path, swizzled scalar writes)
    {
      int kv = l;
#pragma unroll
      for (int i = 0; i < 2; i++) {
        int dbase = w * 8 + i * 32;
        bf16x8 vv = *(const bf16x8*)(Vp + (size_t)(kv0 + kv) * HD + dbase);
#pragma unroll
        for (int jj = 0; jj < 8; jj++) {
          int d = dbase + jj;
          int byteoff = d * 128 + (((kv >> 3) ^ (d & 7)) << 4) + (kv & 7) * 2;
          *(short*)((char*)Vt + byteoff) = vv[jj];
        }
      }
    }
    __syncthreads();

    // ---- QK^T swapped: S^T[kv][q]; A = K rows, B = Q^T
    f32x16 sa[2];
#pragma unroll
    for (int i = 0; i < 16; i++) { sa[0][i] = 0.f; sa[1][i] = 0.f; }
#pragma unroll
    for (int ds = 0; ds < 4; ds++) {
#pragma unroll
      for (int kvb = 0; kvb < 2; kvb++) {
        int kv = kvb * 32 + ln;
        bf16x8 aK = *(const bf16x8*)((const char*)Ks + kv * 128 + (((ds * 2 + hi) ^ (kv & 7)) << 4));
        sa[kvb] = __builtin_amdgcn_mfma_f32_32x32x16_bf16(aK, bQ[ds], sa[kvb], 0, 0, 0);
      }
    }

    // ---- online softmax, log2 domain. Lane holds 32 of 64 kv for its q;
    //      lane^32 holds the other 32 -> one cross-half combine each for max/sum.
    float mx[16];
#pragma unroll
    for (int i = 0; i < 16; i++) mx[i] = fmaxf(sa[0][i], sa[1][i]);
#pragma unroll
    for (int s = 8; s > 0; s >>= 1)
#pragma unroll
      for (int i = 0; i < s; i++) mx[i] = fmaxf(mx[i], mx[i + s]);
    float vmax = fmaxf(mx[0], __shfl_xor(mx[0], 32));
    float m_new = fmaxf(m_run, vmax);
    float alpha = exp2f(m_run - m_new);
    m_run = m_new;

    float sm[16];
#pragma unroll
    for (int i = 0; i < 16; i++) {
      float p0 = exp2f(sa[0][i] - m_new);
      float p1 = exp2f(sa[1][i] - m_new);
      sa[0][i] = p0; sa[1][i] = p1;
      sm[i] = p0 + p1;
    }
#pragma unroll
    for (int s = 8; s > 0; s >>= 1)
#pragma unroll
      for (int i = 0; i < s; i++) sm[i] += sm[i + s];
    float ssum = sm[0] + __shfl_xor(sm[0], 32);
    l_run = l_run * alpha + ssum;

    // ---- P -> bf16 PV B-fragments.
    // Lane holds P^T[kv_rel = kvb*32 + (i&3)+8*(i>>2)+4*hi][q=ln] in sa[kvb][i].
    // B-fragment slice ks needs P^T[ks*16 + hi*8 + j][q=ln], j=0..7:
    //   hi=0 lane: w0,w1 = own A1,A2 (o{0..3});  w2,w3 = partner(hi=1)'s A1,A2 (o{4..7})
    //   hi=1 lane: w0,w1 = partner(hi=0)'s B1,B2 (o{8..11}); w2,w3 = own B1,B2 (o{12..15})
    // Exchange via plain shfl_xor(·,32) full-swap (direction-unambiguous):
    // each lane SENDS (hi ? A : B) and places received words per hi.
    bf16x8 pa[4];
#pragma unroll
    for (int ks = 0; ks < 4; ks++) {
      const int kvb = ks >> 1, hf = (ks & 1) * 8;
      uint32_t A1 = pk2(sa[kvb][hf + 0], sa[kvb][hf + 1]);
      uint32_t A2 = pk2(sa[kvb][hf + 2], sa[kvb][hf + 3]);
      uint32_t B1 = pk2(sa[kvb][hf + 4], sa[kvb][hf + 5]);
      uint32_t B2 = pk2(sa[kvb][hf + 6], sa[kvb][hf + 7]);
      uint32_t send1 = hi ? A1 : B1;
      uint32_t send2 = hi ? A2 : B2;
      uint32_t recv1 = (uint32_t)__shfl_xor((int)send1, 32);
      uint32_t recv2 = (uint32_t)__shfl_xor((int)send2, 32);
      u32x4 wds;
      wds[0] = hi ? recv1 : A1;
      wds[1] = hi ? recv2 : A2;
      wds[2] = hi ? B1 : recv1;
      wds[3] = hi ? B2 : recv2;
      pa[ks] = __builtin_bit_cast(bf16x8, wds);
    }

    // ---- rescale O^T (in-lane: all rows share this lane's q)
#pragma unroll
    for (int i = 0; i < 16; i++) { ot[0][i] *= alpha; ot[1][i] *= alpha; }

    // ---- PV swapped: O^T[d][q] += V^T[d][kv] · P^T[kv][q]
#pragma unroll
    for (int ks = 0; ks < 4; ks++) {
#pragma unroll
      for (int dblk = 0; dblk < 2; dblk++) {
        int d = dblk * 32 + ln;
        bf16x8 aV = *(const bf16x8*)((const char*)Vt + d * 128 + (((ks * 2 + hi) ^ (d & 7)) << 4));
        ot[dblk] = __builtin_amdgcn_mfma_f32_32x32x16_bf16(aV, pa[ks], ot[dblk], 0, 0, 0);
      }
    }
    __syncthreads();
  }

  // ---- epilogue: divide by l, transpose O^T -> O via LDS, coalesced store
  float rl = 1.0f / l_run;
#pragma unroll
  for (int dblk = 0; dblk < 2; dblk++)
#pragma unroll
    for (int r = 0; r < 16; r++) {
      int d = dblk * 32 + (r & 3) + 8 * (r >> 2) + 4 * hi;
      int qrl = w * 32 + ln;
      int byteoff = qrl * 128 + (((d >> 3) ^ (qrl & 7)) << 4) + (d & 7) * 2;
      *(short*)((char*)lds + byteoff) = (short)bfr(ot[dblk][r] * rl);
    }
  __syncthreads();
#pragma unroll
  for (int i = 0; i < 4; i++) {
    int chunk = t * 4 + i;               // 1024 chunks = 128 rows x 8 x 16B
    int row = chunk >> 3, c8 = chunk & 7;
    bf16x8 vv = *(const bf16x8*)((const char*)lds + row * 128 + ((c8 ^ (row & 7)) << 4));
    *(bf16x8*)(ctx + (size_t)(b * SEQ + q0 + row) * EDIM + h * HD + c8 * 8) = vv;
  }
}

// ---------------------------------------------------------------- launch
extern "C" void kernel_launch(void* const* d_in, const int* in_sizes, int n_in,
                              void* d_out, int out_size, void* d_ws, size_t ws_size,
                              hipStream_t stream) {
  const float* q  = (const float*)d_in[0];
  const float* k  = (const float*)d_in[1];
  const float* v  = (const float*)d_in[2];
  const float* wi = (const float*)d_in[3];
  const float* bi = (const float*)d_in[4];
  const float* wo = (const float*)d_in[5];
  const float* bo = (const float*)d_in[6];
  float* out = (float*)d_out;

  short* ws = (short*)d_ws;
  const size_t NTOK = (size_t)TOK * EDIM;
  short* qkv_bf   = ws;
  short* w_in_bf  = qkv_bf + 3 * NTOK;
  short* w_out_bf = w_in_bf + 3 * (size_t)EDIM * EDIM;
  short* proj_bf  = w_out_bf + (size_t)EDIM * EDIM;
  short* ctx_bf   = qkv_bf;   // reuse q region

  cast_f32_bf16<<<dim3((unsigned)(NTOK / 4 / 256)), 256, 0, stream>>>(q, qkv_bf, (int)NTOK);
  cast_f32_bf16<<<dim3((unsigned)(NTOK / 4 / 256)), 256, 0, stream>>>(k, qkv_bf + NTOK, (int)NTOK);
  cast_f32_bf16<<<dim3((unsigned)(NTOK / 4 / 256)), 256, 0, stream>>>(v, qkv_bf + 2 * NTOK, (int)NTOK);
  cast_f32_bf16<<<dim3(3 * EDIM * EDIM / 4 / 256), 256, 0, stream>>>(wi, w_in_bf, 3 * EDIM * EDIM);
  cast_f32_bf16<<<dim3(EDIM * EDIM / 4 / 256), 256, 0, stream>>>(wo, w_out_bf, EDIM * EDIM);

  gemm_bt<0><<<dim3(TOK / 128, EDIM / 128, 3), 256, 0, stream>>>(qkv_bf, w_in_bf, bi, proj_bf);
  attn_fwd2<<<dim3(SEQ / 128, NH, BATCH), 256, 0, stream>>>(proj_bf, ctx_bf);
  gemm_bt<1><<<dim3(TOK / 128, EDIM / 128, 1), 256, 0, stream>>>(ctx_bf, w_out_bf, bo, out);
}

// Round 6
// 209.104 us; speedup vs baseline: 1.2165x; 1.0864x over previous
//
#include <hip/hip_runtime.h>
#include <stdint.h>

#define TOK 8192
#define EDIM 1024
#define NH 16
#define HD 64
#define SEQ 1024
#define BATCH 8

typedef short bf16x8 __attribute__((ext_vector_type(8)));
typedef short bf16x4 __attribute__((ext_vector_type(4)));
typedef float f32x4 __attribute__((ext_vector_type(4)));
typedef float f32x16 __attribute__((ext_vector_type(16)));
typedef unsigned int u32x4 __attribute__((ext_vector_type(4)));

__device__ __forceinline__ short f2bf(float f) {
  union { float f; uint32_t u; } c; c.f = f;
  uint32_t u = c.u;
  u += 0x7FFFu + ((u >> 16) & 1u);   // RNE
  return (short)(u >> 16);
}
__device__ __forceinline__ float bf2f(short h) {
  union { uint32_t u; float f; } c; c.u = ((uint32_t)(uint16_t)h) << 16;
  return c.f;
}
__device__ __forceinline__ uint32_t bfr(float f) {  // cheap round-half-up
  union { float f; uint32_t u; } c; c.f = f;
  return (c.u + 0x8000u) >> 16;
}
__device__ __forceinline__ uint32_t pk2(float lo, float hi_) {
  return (bfr(hi_) << 16) | (bfr(lo) & 0xffffu);
}

#define GLDS16(ldsp, gp) __builtin_amdgcn_global_load_lds( \
    (__attribute__((address_space(1))) void*)(gp),          \
    (__attribute__((address_space(3))) void*)(ldsp), 16, 0, 0)

// ---------------------------------------------------------------- fused cast
// ws dst layout is contiguous: [qkv 3*NTOK][w_in 3*E*E][w_out E*E]
__global__ __launch_bounds__(256) void cast_all(
    const float* __restrict__ q, const float* __restrict__ k,
    const float* __restrict__ v, const float* __restrict__ wi,
    const float* __restrict__ wo, short* __restrict__ dst) {
  const size_t NTOK = (size_t)TOK * EDIM;          // 8388608
  const size_t NWI = 3u * EDIM * EDIM;             // 3145728
  size_t i = ((size_t)blockIdx.x * 256 + threadIdx.x) * 4;
  const float* src;
  if (i < NTOK) src = q + i;
  else if (i < 2 * NTOK) src = k + (i - NTOK);
  else if (i < 3 * NTOK) src = v + (i - 2 * NTOK);
  else if (i < 3 * NTOK + NWI) src = wi + (i - 3 * NTOK);
  else src = wo + (i - 3 * NTOK - NWI);
  float4 f = *(const float4*)src;
  bf16x4 o;
  o[0] = f2bf(f.x); o[1] = f2bf(f.y); o[2] = f2bf(f.z); o[3] = f2bf(f.w);
  *(bf16x4*)(dst + i) = o;
}

// ---------------------------------------------------------------- GEMM (m97 structure)
template<int MODE>
__global__ __launch_bounds__(256)
void gemm_bt(const short* __restrict__ Abase, const short* __restrict__ Wbase,
             const float* __restrict__ biasBase, void* __restrict__ outv) {
  int z = (MODE == 0) ? blockIdx.z : 0;
  const size_t NTOK = (size_t)TOK * EDIM;
  const short* A  = Abase + (size_t)z * NTOK;
  const short* Bw = Wbase + (size_t)z * EDIM * EDIM;
  const float* bias = biasBase + z * EDIM;

  __shared__ short As[128 * 32];
  __shared__ short Bs[128 * 32];

  int t = threadIdx.x;
  int l = t & 63, w = t >> 6;
  int wr = w >> 1, wc = w & 1;
  int fr = l & 15, fg = l >> 4;
  int rowBase = blockIdx.x * 128;
  int colBase = blockIdx.y * 128;

  f32x4 acc[4][4];
  for (int i = 0; i < 4; i++)
    for (int j = 0; j < 4; j++) acc[i][j] = (f32x4){0.f, 0.f, 0.f, 0.f};

  int sRow = t >> 2;
  int sCol = (t & 3) * 8;
  const short* aSrc = A  + (size_t)(rowBase + sRow) * EDIM + sCol;
  const short* bSrc = Bw + (size_t)(colBase + sRow) * EDIM + sCol;
  short* aDst = &As[t * 8];
  short* bDst = &Bs[t * 8];

  for (int k0 = 0; k0 < EDIM; k0 += 32) {
    GLDS16(aDst,        aSrc + k0);
    GLDS16(aDst + 2048, aSrc + (size_t)64 * EDIM + k0);
    GLDS16(bDst,        bSrc + k0);
    GLDS16(bDst + 2048, bSrc + (size_t)64 * EDIM + k0);
    __syncthreads();

    bf16x8 af[4], bf_[4];
    for (int mi = 0; mi < 4; mi++)
      af[mi] = *(const bf16x8*)&As[(wr * 64 + mi * 16 + fr) * 32 + fg * 8];
    for (int ni = 0; ni < 4; ni++)
      bf_[ni] = *(const bf16x8*)&Bs[(wc * 64 + ni * 16 + fr) * 32 + fg * 8];
    for (int mi = 0; mi < 4; mi++)
      for (int ni = 0; ni < 4; ni++)
        acc[mi][ni] = __builtin_amdgcn_mfma_f32_16x16x32_bf16(af[mi], bf_[ni], acc[mi][ni], 0, 0, 0);
    __syncthreads();
  }

  for (int mi = 0; mi < 4; mi++)
    for (int ni = 0; ni < 4; ni++)
      for (int r = 0; r < 4; r++) {
        int grow = rowBase + wr * 64 + mi * 16 + fg * 4 + r;
        int gcol = colBase + wc * 64 + ni * 16 + fr;
        float v = acc[mi][ni][r] + bias[gcol];
        if (MODE == 0) {
          int b_ = grow >> 10, s_ = grow & 1023;
          int h_ = gcol >> 6,  d_ = gcol & 63;
          short* outp = (short*)outv + (size_t)z * NTOK;
          outp[((size_t)((b_ * NH + h_) * SEQ + s_) << 6) | d_] = f2bf(v);
        } else {
          ((float*)outv)[(size_t)grow * EDIM + gcol] = v;
        }
      }
}

// ---------------------------------------------------------------- flash attention v4
// = R4's PASSING attn_fwd2 structure (swapped QK^T / in-reg softmax /
//   shfl-exchange P / swizzled Vt + ds_read_b128 PV / LDS-transpose epilogue)
// + double-buffered K/V with ONE barrier per iter:
//     K(jt+1) via global_load_lds and V(jt+1) global->reg issued at iter top;
//     V ds_writes placed AFTER PV (T14 write-late); barrier completes both.
// + defer-max (T13), vectorized l accumulation, setprio around MFMA clusters.
// LDS: 2 bufs x (Ks 8KB + Vt 8KB) = 32KB; epilogue reuses first 16KB.
__global__ __launch_bounds__(256)
void attn_fwd4(const short* __restrict__ proj, short* __restrict__ ctx) {
  __shared__ short lds[16384];             // 32 KiB

  const int t = threadIdx.x;
  const int l = t & 63, w = t >> 6;
  const int ln = l & 31, hi = l >> 5;
  const int qt = blockIdx.x, h = blockIdx.y, b = blockIdx.z;

  const size_t NTOK = (size_t)TOK * EDIM;
  const size_t headOff = (size_t)(b * NH + h) * SEQ * HD;
  const short* Qp = proj + headOff;
  const short* Kp = proj + NTOK + headOff;
  const short* Vp = proj + 2 * NTOK + headOff;

  const int q0 = qt * 128;
  const int qrow = q0 + w * 32 + ln;

  // staging thread-constants (K: pre-swizzled source, linear LDS dest)
  const int kRow = t >> 3;                          // 0..31
  const int kCol = ((t & 7) ^ (kRow & 7)) << 3;     // shorts
  // V register-stage: lane kv = l, two d-blocks of 8
  const int vd0 = w * 8;                            // dbase for i=0 (i=1: +32)

  // Q^T B-fragments, scaled by 0.125*log2(e)
  const float qscale = 0.18033688011112042f;
  bf16x8 bQ[4];
#pragma unroll
  for (int ds = 0; ds < 4; ds++) {
    bf16x8 v = *(const bf16x8*)(Qp + (size_t)qrow * HD + ds * 16 + hi * 8);
#pragma unroll
    for (int j = 0; j < 8; j++) v[j] = (short)bfr(bf2f(v[j]) * qscale);
    bQ[ds] = v;
  }

  float m_run = -3.0e38f;
  float l_acc[16];
  f32x16 ot[2];
#pragma unroll
  for (int i = 0; i < 16; i++) { l_acc[i] = 0.f; ot[0][i] = 0.f; ot[1][i] = 0.f; }

  // ---- prologue: stage tile 0 into buf 0
  {
    const short* Ksrc = Kp + (size_t)kRow * HD + kCol;
    GLDS16((char*)lds + t * 16,        Ksrc);
    GLDS16((char*)lds + 4096 + t * 16, Ksrc + 32 * HD);
    bf16x8 v0 = *(const bf16x8*)(Vp + (size_t)l * HD + vd0);
    bf16x8 v1 = *(const bf16x8*)(Vp + (size_t)l * HD + vd0 + 32);
    char* VtB = (char*)lds + 8192;
#pragma unroll
    for (int jj = 0; jj < 8; jj++) {
      int d0 = vd0 + jj, d1 = vd0 + 32 + jj;
      *(short*)(VtB + d0 * 128 + (((l >> 3) ^ (d0 & 7)) << 4) + (l & 7) * 2) = v0[jj];
      *(short*)(VtB + d1 * 128 + (((l >> 3) ^ (d1 & 7)) << 4) + (l & 7) * 2) = v1[jj];
    }
  }
  __syncthreads();

  for (int jt = 0; jt < SEQ / 64; jt++) {
    const int bufByte = (jt & 1) << 14;
    const int nb = bufByte ^ (1 << 14);
    const bool have_next = (jt + 1 < SEQ / 64);

    // ---- issue next tile's loads NOW (complete under this tile's compute)
    bf16x8 nv0, nv1;
    if (have_next) {
      const int kv1 = (jt + 1) * 64;
      const short* Ksrc = Kp + (size_t)(kv1 + kRow) * HD + kCol;
      GLDS16((char*)lds + nb + t * 16,        Ksrc);
      GLDS16((char*)lds + nb + 4096 + t * 16, Ksrc + 32 * HD);
      nv0 = *(const bf16x8*)(Vp + (size_t)(kv1 + l) * HD + vd0);
      nv1 = *(const bf16x8*)(Vp + (size_t)(kv1 + l) * HD + vd0 + 32);
    }

    // ---- QK^T swapped: S^T[kv][q]
    f32x16 sa[2];
#pragma unroll
    for (int i = 0; i < 16; i++) { sa[0][i] = 0.f; sa[1][i] = 0.f; }
    __builtin_amdgcn_s_setprio(1);
#pragma unroll
    for (int ds = 0; ds < 4; ds++) {
#pragma unroll
      for (int kvb = 0; kvb < 2; kvb++) {
        int kv = kvb * 32 + ln;
        bf16x8 aK = *(const bf16x8*)((const char*)lds + bufByte + kv * 128 +
                                     (((ds * 2 + hi) ^ (kv & 7)) << 4));
        sa[kvb] = __builtin_amdgcn_mfma_f32_32x32x16_bf16(aK, bQ[ds], sa[kvb], 0, 0, 0);
      }
    }
    __builtin_amdgcn_s_setprio(0);

    // ---- online softmax, log2 domain, defer-max (T13)
    float mx[16];
#pragma unroll
    for (int i = 0; i < 16; i++) mx[i] = fmaxf(sa[0][i], sa[1][i]);
#pragma unroll
    for (int s = 8; s > 0; s >>= 1)
#pragma unroll
      for (int i = 0; i < s; i++) mx[i] = fmaxf(mx[i], mx[i + s]);
    float vmax = fmaxf(mx[0], __shfl_xor(mx[0], 32));

    int grow = !__all(vmax <= m_run + 8.0f);
    float alpha = 1.0f;
    if (grow) {
      float m_new = fmaxf(m_run, vmax);
      alpha = exp2f(m_run - m_new);
      m_run = m_new;
    }
#pragma unroll
    for (int i = 0; i < 16; i++) {
      float p0 = exp2f(sa[0][i] - m_run);
      float p1 = exp2f(sa[1][i] - m_run);
      sa[0][i] = p0; sa[1][i] = p1;
      l_acc[i] = l_acc[i] * alpha + (p0 + p1);
    }

    // ---- P -> bf16 PV B-fragments (exchange via shfl_xor(32) full-swap)
    bf16x8 pa[4];
#pragma unroll
    for (int ks = 0; ks < 4; ks++) {
      const int kvb = ks >> 1, hf = (ks & 1) * 8;
      uint32_t A1 = pk2(sa[kvb][hf + 0], sa[kvb][hf + 1]);
      uint32_t A2 = pk2(sa[kvb][hf + 2], sa[kvb][hf + 3]);
      uint32_t B1 = pk2(sa[kvb][hf + 4], sa[kvb][hf + 5]);
      uint32_t B2 = pk2(sa[kvb][hf + 6], sa[kvb][hf + 7]);
      uint32_t send1 = hi ? A1 : B1;
      uint32_t send2 = hi ? A2 : B2;
      uint32_t recv1 = (uint32_t)__shfl_xor((int)send1, 32);
      uint32_t recv2 = (uint32_t)__shfl_xor((int)send2, 32);
      u32x4 wds;
      wds[0] = hi ? recv1 : A1;
      wds[1] = hi ? recv2 : A2;
      wds[2] = hi ? B1 : recv1;
      wds[3] = hi ? B2 : recv2;
      pa[ks] = __builtin_bit_cast(bf16x8, wds);
    }

    // ---- rescale O^T (in-lane), then PV from swizzled Vt (R4 proven path)
    if (grow) {
#pragma unroll
      for (int i = 0; i < 16; i++) { ot[0][i] *= alpha; ot[1][i] *= alpha; }
    }
    const char* VtB = (const char*)lds + bufByte + 8192;
    __builtin_amdgcn_s_setprio(1);
#pragma unroll
    for (int ks = 0; ks < 4; ks++) {
#pragma unroll
      for (int dblk = 0; dblk < 2; dblk++) {
        int d = dblk * 32 + ln;
        bf16x8 aV = *(const bf16x8*)(VtB + d * 128 + (((ks * 2 + hi) ^ (d & 7)) << 4));
        ot[dblk] = __builtin_amdgcn_mfma_f32_32x32x16_bf16(aV, pa[ks], ot[dblk], 0, 0, 0);
      }
    }
    __builtin_amdgcn_s_setprio(0);

    // ---- write next tile's V into buf^1 (T14 write-late: loads have had the
    //      whole tile's compute to land; compiler inserts the vmcnt wait here)
    if (have_next) {
      char* VtN = (char*)lds + nb + 8192;
#pragma unroll
      for (int jj = 0; jj < 8; jj++) {
        int d0 = vd0 + jj, d1 = vd0 + 32 + jj;
        *(short*)(VtN + d0 * 128 + (((l >> 3) ^ (d0 & 7)) << 4) + (l & 7) * 2) = nv0[jj];
        *(short*)(VtN + d1 * 128 + (((l >> 3) ^ (d1 & 7)) << 4) + (l & 7) * 2) = nv1[jj];
      }
    }

    // one barrier per iter: its waitcnt drain also completes the K staging
    __syncthreads();
  }

  // ---- final softmax denominator
#pragma unroll
  for (int s = 8; s > 0; s >>= 1)
#pragma unroll
    for (int i = 0; i < s; i++) l_acc[i] += l_acc[i + s];
  float l_run = l_acc[0] + __shfl_xor(l_acc[0], 32);
  float rl = 1.0f / l_run;

  // ---- epilogue: transpose O^T -> O via LDS (first 16KB), coalesced store
#pragma unroll
  for (int dblk = 0; dblk < 2; dblk++)
#pragma unroll
    for (int r = 0; r < 16; r++) {
      int d = dblk * 32 + (r & 3) + 8 * (r >> 2) + 4 * hi;
      int qrl = w * 32 + ln;
      int byteoff = qrl * 128 + (((d >> 3) ^ (qrl & 7)) << 4) + (d & 7) * 2;
      *(short*)((char*)lds + byteoff) = (short)bfr(ot[dblk][r] * rl);
    }
  __syncthreads();
#pragma unroll
  for (int i = 0; i < 4; i++) {
    int chunk = t * 4 + i;               // 1024 chunks = 128 rows x 8 x 16B
    int row = chunk >> 3, c8 = chunk & 7;
    bf16x8 vv = *(const bf16x8*)((const char*)lds + row * 128 + ((c8 ^ (row & 7)) << 4));
    *(bf16x8*)(ctx + (size_t)(b * SEQ + q0 + row) * EDIM + h * HD + c8 * 8) = vv;
  }
}

// ---------------------------------------------------------------- launch
extern "C" void kernel_launch(void* const* d_in, const int* in_sizes, int n_in,
                              void* d_out, int out_size, void* d_ws, size_t ws_size,
                              hipStream_t stream) {
  const float* q  = (const float*)d_in[0];
  const float* k  = (const float*)d_in[1];
  const float* v  = (const float*)d_in[2];
  const float* wi = (const float*)d_in[3];
  const float* bi = (const float*)d_in[4];
  const float* wo = (const float*)d_in[5];
  const float* bo = (const float*)d_in[6];
  float* out = (float*)d_out;

  short* ws = (short*)d_ws;
  const size_t NTOK = (size_t)TOK * EDIM;
  short* qkv_bf   = ws;
  short* w_in_bf  = qkv_bf + 3 * NTOK;
  short* w_out_bf = w_in_bf + 3 * (size_t)EDIM * EDIM;
  short* proj_bf  = w_out_bf + (size_t)EDIM * EDIM;
  short* ctx_bf   = qkv_bf;   // reuse q region

  const size_t totalCast = 3 * NTOK + 3 * (size_t)EDIM * EDIM + (size_t)EDIM * EDIM;
  cast_all<<<dim3((unsigned)(totalCast / 4 / 256)), 256, 0, stream>>>(q, k, v, wi, wo, qkv_bf);

  gemm_bt<0><<<dim3(TOK / 128, EDIM / 128, 3), 256, 0, stream>>>(qkv_bf, w_in_bf, bi, proj_bf);
  attn_fwd4<<<dim3(SEQ / 128, NH, BATCH), 256, 0, stream>>>(proj_bf, ctx_bf);
  gemm_bt<1><<<dim3(TOK / 128, EDIM / 128, 1), 256, 0, stream>>>(ctx_bf, w_out_bf, bo, out);
}

// Round 7
// 199.350 us; speedup vs baseline: 1.2760x; 1.0489x over previous
//
#include <hip/hip_runtime.h>
#include <stdint.h>

#define TOK 8192
#define EDIM 1024
#define NH 16
#define HD 64
#define SEQ 1024
#define BATCH 8

typedef short bf16x8 __attribute__((ext_vector_type(8)));
typedef short bf16x4 __attribute__((ext_vector_type(4)));
typedef float f32x4 __attribute__((ext_vector_type(4)));
typedef float f32x16 __attribute__((ext_vector_type(16)));
typedef unsigned int u32x2 __attribute__((ext_vector_type(2)));
typedef unsigned int u32x4 __attribute__((ext_vector_type(4)));

__device__ __forceinline__ short f2bf(float f) {
  union { float f; uint32_t u; } c; c.f = f;
  uint32_t u = c.u;
  u += 0x7FFFu + ((u >> 16) & 1u);   // RNE
  return (short)(u >> 16);
}
__device__ __forceinline__ float bf2f(short h) {
  union { uint32_t u; float f; } c; c.u = ((uint32_t)(uint16_t)h) << 16;
  return c.f;
}
__device__ __forceinline__ uint32_t bfr(float f) {  // cheap round-half-up
  union { float f; uint32_t u; } c; c.f = f;
  return (c.u + 0x8000u) >> 16;
}
// pack 2 f32 -> 2 bf16 in one instr (lo -> low half)
__device__ __forceinline__ uint32_t cvtpk(float lo, float hi_) {
  uint32_t r;
  asm("v_cvt_pk_bf16_f32 %0, %1, %2" : "=v"(r) : "v"(lo), "v"(hi_));
  return r;
}

#define GLDS16(ldsp, gp) __builtin_amdgcn_global_load_lds( \
    (__attribute__((address_space(1))) void*)(gp),          \
    (__attribute__((address_space(3))) void*)(ldsp), 16, 0, 0)

// ---------------------------------------------------------------- fused cast
__global__ __launch_bounds__(256) void cast_all(
    const float* __restrict__ q, const float* __restrict__ k,
    const float* __restrict__ v, const float* __restrict__ wi,
    const float* __restrict__ wo, short* __restrict__ dst) {
  const size_t NTOK = (size_t)TOK * EDIM;          // 8388608
  const size_t NWI = 3u * EDIM * EDIM;             // 3145728
  size_t i = ((size_t)blockIdx.x * 256 + threadIdx.x) * 4;
  const float* src;
  if (i < NTOK) src = q + i;
  else if (i < 2 * NTOK) src = k + (i - NTOK);
  else if (i < 3 * NTOK) src = v + (i - 2 * NTOK);
  else if (i < 3 * NTOK + NWI) src = wi + (i - 3 * NTOK);
  else src = wo + (i - 3 * NTOK - NWI);
  float4 f = *(const float4*)src;
  bf16x4 o;
  o[0] = f2bf(f.x); o[1] = f2bf(f.y); o[2] = f2bf(f.z); o[3] = f2bf(f.w);
  *(bf16x4*)(dst + i) = o;
}

// ---------------------------------------------------------------- GEMM (m97 structure)
template<int MODE>
__global__ __launch_bounds__(256)
void gemm_bt(const short* __restrict__ Abase, const short* __restrict__ Wbase,
             const float* __restrict__ biasBase, void* __restrict__ outv) {
  int z = (MODE == 0) ? blockIdx.z : 0;
  const size_t NTOK = (size_t)TOK * EDIM;
  const short* A  = Abase + (size_t)z * NTOK;
  const short* Bw = Wbase + (size_t)z * EDIM * EDIM;
  const float* bias = biasBase + z * EDIM;

  __shared__ short As[128 * 32];
  __shared__ short Bs[128 * 32];

  int t = threadIdx.x;
  int l = t & 63, w = t >> 6;
  int wr = w >> 1, wc = w & 1;
  int fr = l & 15, fg = l >> 4;
  int rowBase = blockIdx.x * 128;
  int colBase = blockIdx.y * 128;

  f32x4 acc[4][4];
  for (int i = 0; i < 4; i++)
    for (int j = 0; j < 4; j++) acc[i][j] = (f32x4){0.f, 0.f, 0.f, 0.f};

  int sRow = t >> 2;
  int sCol = (t & 3) * 8;
  const short* aSrc = A  + (size_t)(rowBase + sRow) * EDIM + sCol;
  const short* bSrc = Bw + (size_t)(colBase + sRow) * EDIM + sCol;
  short* aDst = &As[t * 8];
  short* bDst = &Bs[t * 8];

  for (int k0 = 0; k0 < EDIM; k0 += 32) {
    GLDS16(aDst,        aSrc + k0);
    GLDS16(aDst + 2048, aSrc + (size_t)64 * EDIM + k0);
    GLDS16(bDst,        bSrc + k0);
    GLDS16(bDst + 2048, bSrc + (size_t)64 * EDIM + k0);
    __syncthreads();

    bf16x8 af[4], bf_[4];
    for (int mi = 0; mi < 4; mi++)
      af[mi] = *(const bf16x8*)&As[(wr * 64 + mi * 16 + fr) * 32 + fg * 8];
    for (int ni = 0; ni < 4; ni++)
      bf_[ni] = *(const bf16x8*)&Bs[(wc * 64 + ni * 16 + fr) * 32 + fg * 8];
    for (int mi = 0; mi < 4; mi++)
      for (int ni = 0; ni < 4; ni++)
        acc[mi][ni] = __builtin_amdgcn_mfma_f32_16x16x32_bf16(af[mi], bf_[ni], acc[mi][ni], 0, 0, 0);
    __syncthreads();
  }

  for (int mi = 0; mi < 4; mi++)
    for (int ni = 0; ni < 4; ni++)
      for (int r = 0; r < 4; r++) {
        int grow = rowBase + wr * 64 + mi * 16 + fg * 4 + r;
        int gcol = colBase + wc * 64 + ni * 16 + fr;
        float v = acc[mi][ni][r] + bias[gcol];
        if (MODE == 0) {
          int b_ = grow >> 10, s_ = grow & 1023;
          int h_ = gcol >> 6,  d_ = gcol & 63;
          short* outp = (short*)outv + (size_t)z * NTOK;
          outp[((size_t)((b_ * NH + h_) * SEQ + s_) << 6) | d_] = f2bf(v);
        } else {
          ((float*)outv)[(size_t)grow * EDIM + gcol] = v;
        }
      }
}

// ---------------------------------------------------------------- flash attention v5
// R6 structure (dbuf, 1 barrier/iter, defer-max, write-late V) plus:
//  - cvt_pk_bf16_f32 P-pack (1 instr per pair)
//  - permlane32_swap P-exchange: {w0,w2} = swap(A1,B1), {w1,w3} = swap(A2,B2)
//    (derived from the working shfl path: w0 = A1[0:31]||B1[0:31], etc.)
//  - max3-shaped reduction tree
//  - l accumulator compressed to 4 regs (ps[4] per tile)
//  - XCD-aware block remap: all 8 q-tiles of one head share id%8 -> same XCD L2
__global__ __launch_bounds__(256)
void attn_fwd5(const short* __restrict__ proj, short* __restrict__ ctx) {
  __shared__ short lds[16384];             // 32 KiB

  const int t = threadIdx.x;
  const int l = t & 63, w = t >> 6;
  const int ln = l & 31, hi = l >> 5;

  // bijective remap of linear block id: qt in bits [3:5], head-low in [0:2],
  // head-high in [6:9] -> id%8 = head&7 (8 q-tiles of a head share an XCD)
  const int n = blockIdx.x + 8 * (blockIdx.y + 16 * blockIdx.z);
  const int qt = (n >> 3) & 7;
  const int hl = (n & 7) | ((n >> 6) << 3);   // 0..127
  const int h = hl & 15, b = hl >> 4;

  const size_t NTOK = (size_t)TOK * EDIM;
  const size_t headOff = (size_t)(b * NH + h) * SEQ * HD;
  const short* Qp = proj + headOff;
  const short* Kp = proj + NTOK + headOff;
  const short* Vp = proj + 2 * NTOK + headOff;

  const int q0 = qt * 128;
  const int qrow = q0 + w * 32 + ln;

  // staging thread-constants (K: pre-swizzled source, linear LDS dest)
  const int kRow = t >> 3;                          // 0..31
  const int kCol = ((t & 7) ^ (kRow & 7)) << 3;     // shorts
  const int vd0 = w * 8;                            // V dbase (i=1: +32)

  // Q^T B-fragments, scaled by 0.125*log2(e)
  const float qscale = 0.18033688011112042f;
  bf16x8 bQ[4];
#pragma unroll
  for (int ds = 0; ds < 4; ds++) {
    bf16x8 v = *(const bf16x8*)(Qp + (size_t)qrow * HD + ds * 16 + hi * 8);
#pragma unroll
    for (int j = 0; j < 8; j++) v[j] = (short)bfr(bf2f(v[j]) * qscale);
    bQ[ds] = v;
  }

  float m_run = -3.0e38f;
  float l_acc[4] = {0.f, 0.f, 0.f, 0.f};
  f32x16 ot[2];
#pragma unroll
  for (int i = 0; i < 16; i++) { ot[0][i] = 0.f; ot[1][i] = 0.f; }

  // ---- prologue: stage tile 0 into buf 0
  {
    const short* Ksrc = Kp + (size_t)kRow * HD + kCol;
    GLDS16((char*)lds + t * 16,        Ksrc);
    GLDS16((char*)lds + 4096 + t * 16, Ksrc + 32 * HD);
    bf16x8 v0 = *(const bf16x8*)(Vp + (size_t)l * HD + vd0);
    bf16x8 v1 = *(const bf16x8*)(Vp + (size_t)l * HD + vd0 + 32);
    char* VtB = (char*)lds + 8192;
#pragma unroll
    for (int jj = 0; jj < 8; jj++) {
      int d0 = vd0 + jj, d1 = vd0 + 32 + jj;
      *(short*)(VtB + d0 * 128 + (((l >> 3) ^ (d0 & 7)) << 4) + (l & 7) * 2) = v0[jj];
      *(short*)(VtB + d1 * 128 + (((l >> 3) ^ (d1 & 7)) << 4) + (l & 7) * 2) = v1[jj];
    }
  }
  __syncthreads();

  for (int jt = 0; jt < SEQ / 64; jt++) {
    const int bufByte = (jt & 1) << 14;
    const int nb = bufByte ^ (1 << 14);
    const bool have_next = (jt + 1 < SEQ / 64);

    // ---- issue next tile's loads NOW (complete under this tile's compute)
    bf16x8 nv0, nv1;
    if (have_next) {
      const int kv1 = (jt + 1) * 64;
      const short* Ksrc = Kp + (size_t)(kv1 + kRow) * HD + kCol;
      GLDS16((char*)lds + nb + t * 16,        Ksrc);
      GLDS16((char*)lds + nb + 4096 + t * 16, Ksrc + 32 * HD);
      nv0 = *(const bf16x8*)(Vp + (size_t)(kv1 + l) * HD + vd0);
      nv1 = *(const bf16x8*)(Vp + (size_t)(kv1 + l) * HD + vd0 + 32);
    }

    // ---- QK^T swapped: S^T[kv][q]
    f32x16 sa[2];
#pragma unroll
    for (int i = 0; i < 16; i++) { sa[0][i] = 0.f; sa[1][i] = 0.f; }
    __builtin_amdgcn_s_setprio(1);
#pragma unroll
    for (int ds = 0; ds < 4; ds++) {
#pragma unroll
      for (int kvb = 0; kvb < 2; kvb++) {
        int kv = kvb * 32 + ln;
        bf16x8 aK = *(const bf16x8*)((const char*)lds + bufByte + kv * 128 +
                                     (((ds * 2 + hi) ^ (kv & 7)) << 4));
        sa[kvb] = __builtin_amdgcn_mfma_f32_32x32x16_bf16(aK, bQ[ds], sa[kvb], 0, 0, 0);
      }
    }
    __builtin_amdgcn_s_setprio(0);

    // ---- max via max3-shaped tree (32 values)
    float tr[11];
#pragma unroll
    for (int j = 0; j < 10; j++) {
      float a = (3 * j + 0 < 16) ? sa[0][3 * j + 0] : sa[1][3 * j - 16];
      float b2 = (3 * j + 1 < 16) ? sa[0][3 * j + 1] : sa[1][3 * j - 15];
      float c = (3 * j + 2 < 16) ? sa[0][3 * j + 2] : sa[1][3 * j - 14];
      tr[j] = fmaxf(fmaxf(a, b2), c);
    }
    tr[10] = fmaxf(sa[1][14], sa[1][15]);
    float u0 = fmaxf(fmaxf(tr[0], tr[1]), tr[2]);
    float u1 = fmaxf(fmaxf(tr[3], tr[4]), tr[5]);
    float u2 = fmaxf(fmaxf(tr[6], tr[7]), tr[8]);
    float u3 = fmaxf(tr[9], tr[10]);
    float vmax = fmaxf(fmaxf(fmaxf(u0, u1), u2), u3);
    vmax = fmaxf(vmax, __shfl_xor(vmax, 32));

    // ---- online softmax, log2 domain, defer-max (T13)
    int grow = !__all(vmax <= m_run + 8.0f);
    float alpha = 1.0f;
    if (grow) {
      float m_new = fmaxf(m_run, vmax);
      alpha = exp2f(m_run - m_new);
      m_run = m_new;
    }
    float ps[4] = {0.f, 0.f, 0.f, 0.f};
#pragma unroll
    for (int i = 0; i < 16; i++) {
      float p0 = exp2f(sa[0][i] - m_run);
      float p1 = exp2f(sa[1][i] - m_run);
      sa[0][i] = p0; sa[1][i] = p1;
      ps[i & 3] += p0 + p1;
    }
#pragma unroll
    for (int j = 0; j < 4; j++) l_acc[j] = l_acc[j] * alpha + ps[j];

    // ---- P -> bf16 PV B-fragments: cvt_pk + permlane32_swap
    bf16x8 pa[4];
#pragma unroll
    for (int ks = 0; ks < 4; ks++) {
      const int kvb = ks >> 1, hf = (ks & 1) * 8;
      uint32_t A1 = cvtpk(sa[kvb][hf + 0], sa[kvb][hf + 1]);
      uint32_t A2 = cvtpk(sa[kvb][hf + 2], sa[kvb][hf + 3]);
      uint32_t B1 = cvtpk(sa[kvb][hf + 4], sa[kvb][hf + 5]);
      uint32_t B2 = cvtpk(sa[kvb][hf + 6], sa[kvb][hf + 7]);
      u32x4 wds;
#if __has_builtin(__builtin_amdgcn_permlane32_swap)
      u32x2 r13 = __builtin_amdgcn_permlane32_swap(A1, B1, false, false);
      u32x2 r24 = __builtin_amdgcn_permlane32_swap(A2, B2, false, false);
      wds[0] = r13[0]; wds[2] = r13[1];
      wds[1] = r24[0]; wds[3] = r24[1];
#else
      uint32_t send1 = hi ? A1 : B1;
      uint32_t send2 = hi ? A2 : B2;
      uint32_t recv1 = (uint32_t)__shfl_xor((int)send1, 32);
      uint32_t recv2 = (uint32_t)__shfl_xor((int)send2, 32);
      wds[0] = hi ? recv1 : A1;
      wds[1] = hi ? recv2 : A2;
      wds[2] = hi ? B1 : recv1;
      wds[3] = hi ? B2 : recv2;
#endif
      pa[ks] = __builtin_bit_cast(bf16x8, wds);
    }

    // ---- rescale O^T (in-lane), then PV from swizzled Vt
    if (grow) {
#pragma unroll
      for (int i = 0; i < 16; i++) { ot[0][i] *= alpha; ot[1][i] *= alpha; }
    }
    const char* VtB = (const char*)lds + bufByte + 8192;
    __builtin_amdgcn_s_setprio(1);
#pragma unroll
    for (int ks = 0; ks < 4; ks++) {
#pragma unroll
      for (int dblk = 0; dblk < 2; dblk++) {
        int d = dblk * 32 + ln;
        bf16x8 aV = *(const bf16x8*)(VtB + d * 128 + (((ks * 2 + hi) ^ (d & 7)) << 4));
        ot[dblk] = __builtin_amdgcn_mfma_f32_32x32x16_bf16(aV, pa[ks], ot[dblk], 0, 0, 0);
      }
    }
    __builtin_amdgcn_s_setprio(0);

    // ---- write next tile's V into buf^1 (T14 write-late)
    if (have_next) {
      char* VtN = (char*)lds + nb + 8192;
#pragma unroll
      for (int jj = 0; jj < 8; jj++) {
        int d0 = vd0 + jj, d1 = vd0 + 32 + jj;
        *(short*)(VtN + d0 * 128 + (((l >> 3) ^ (d0 & 7)) << 4) + (l & 7) * 2) = nv0[jj];
        *(short*)(VtN + d1 * 128 + (((l >> 3) ^ (d1 & 7)) << 4) + (l & 7) * 2) = nv1[jj];
      }
    }

    // one barrier per iter: its waitcnt drain also completes the K staging
    __syncthreads();
  }

  // ---- final softmax denominator
  float l_run = (l_acc[0] + l_acc[1]) + (l_acc[2] + l_acc[3]);
  l_run += __shfl_xor(l_run, 32);
  float rl = 1.0f / l_run;

  // ---- epilogue: transpose O^T -> O via LDS (first 16KB), coalesced store
#pragma unroll
  for (int dblk = 0; dblk < 2; dblk++)
#pragma unroll
    for (int r = 0; r < 16; r++) {
      int d = dblk * 32 + (r & 3) + 8 * (r >> 2) + 4 * hi;
      int qrl = w * 32 + ln;
      int byteoff = qrl * 128 + (((d >> 3) ^ (qrl & 7)) << 4) + (d & 7) * 2;
      *(short*)((char*)lds + byteoff) = (short)bfr(ot[dblk][r] * rl);
    }
  __syncthreads();
#pragma unroll
  for (int i = 0; i < 4; i++) {
    int chunk = t * 4 + i;               // 1024 chunks = 128 rows x 8 x 16B
    int row = chunk >> 3, c8 = chunk & 7;
    bf16x8 vv = *(const bf16x8*)((const char*)lds + row * 128 + ((c8 ^ (row & 7)) << 4));
    *(bf16x8*)(ctx + (size_t)(b * SEQ + q0 + row) * EDIM + h * HD + c8 * 8) = vv;
  }
}

// ---------------------------------------------------------------- launch
extern "C" void kernel_launch(void* const* d_in, const int* in_sizes, int n_in,
                              void* d_out, int out_size, void* d_ws, size_t ws_size,
                              hipStream_t stream) {
  const float* q  = (const float*)d_in[0];
  const float* k  = (const float*)d_in[1];
  const float* v  = (const float*)d_in[2];
  const float* wi = (const float*)d_in[3];
  const float* bi = (const float*)d_in[4];
  const float* wo = (const float*)d_in[5];
  const float* bo = (const float*)d_in[6];
  float* out = (float*)d_out;

  short* ws = (short*)d_ws;
  const size_t NTOK = (size_t)TOK * EDIM;
  short* qkv_bf   = ws;
  short* w_in_bf  = qkv_bf + 3 * NTOK;
  short* w_out_bf = w_in_bf + 3 * (size_t)EDIM * EDIM;
  short* proj_bf  = w_out_bf + (size_t)EDIM * EDIM;
  short* ctx_bf   = qkv_bf;   // reuse q region

  const size_t totalCast = 3 * NTOK + 3 * (size_t)EDIM * EDIM + (size_t)EDIM * EDIM;
  cast_all<<<dim3((unsigned)(totalCast / 4 / 256)), 256, 0, stream>>>(q, k, v, wi, wo, qkv_bf);

  gemm_bt<0><<<dim3(TOK / 128, EDIM / 128, 3), 256, 0, stream>>>(qkv_bf, w_in_bf, bi, proj_bf);
  attn_fwd5<<<dim3(SEQ / 128, NH, BATCH), 256, 0, stream>>>(proj_bf, ctx_bf);
  gemm_bt<1><<<dim3(TOK / 128, EDIM / 128, 1), 256, 0, stream>>>(ctx_bf, w_out_bf, bo, out);
}